// Round 5
// baseline (762.279 us; speedup 1.0000x reference)
//
#include <hip/hip_runtime.h>
#include <cmath>

// out = (log(|DCT2(x)| + 1e-13) - mean) / std,  x: [384][256][256] f32.
// CORRECTNESS CONTRACT (R1-R3 evidence): the np reference accumulates in f32;
// near-zero DCT coefficients are f32 rounding NOISE and log() demands we
// reproduce that noise ~exactly. Every output element must be a single
// sequential fmaf chain, i ascending (stage 1) / j ascending (stage 2), with
// the stage-1 result rounded to f32 (materialized). NO MFMA, NO split accums.
//
// R4: two-kernel split, 449us total (y=176.7us vs 82us FMA floor, VALUBusy
// 68%). Remaining loss = unhidden global-load latency (loads issued after
// barrier, consumed immediately) + 64 barriers/block. R5: register-prefetch
// pipeline (issue chunk c+1's global loads BEFORE computing chunk c) +
// 16-row chunks (half the barriers) + transposed T1 staging in y so the
// a-operand is one broadcast ds_read_b128 per step.

#define HN    256
#define NIMG  384

// ---- f32 basis: Tdf[i][k] = (float)( cos(pi*(2i+1)*k/512) * s(k) ) --------
__global__ void basis_init(float* __restrict__ Tdf) {
    int idx = blockIdx.x * 256 + threadIdx.x;   // 65536
    int i = idx >> 8, k = idx & 255;
    double c = cos(M_PI * (2.0 * i + 1.0) * (double)k / 512.0);
    double s = (k == 0) ? sqrt(1.0 / 256.0) : sqrt(2.0 / 256.0);
    Tdf[idx] = (float)(c * s);
}

// ======================= two-kernel path ===================================
// Kernel A: T1[img][k1][j] = sum_i Tdf[i][k1] * X[img][i][j]   (i ascending)
// Block: one image x 64-wide j-slab; thread owns 16 k1 x 4 j = 64 accs.
__global__ __launch_bounds__(256, 4) void t1_kernel(
    const float* __restrict__ X, const float* __restrict__ Tdf,
    float* __restrict__ T1)
{
    __shared__ float Xs[16][64];     // X i-chunk, j-slab        (4 KB)
    __shared__ float CHs[16][HN];    // basis rows i0..i0+15     (16 KB)

    const int t   = threadIdx.x;
    const int img = blockIdx.x >> 2;
    const int js  = (blockIdx.x & 3) * 64;
    const float* __restrict__ Xi = X + (size_t)img * (HN * HN);

    const int ci = t & 15;   // j  = js + 4*ci + jr
    const int ib = t >> 4;   // k1 = 64*s + 4*ib + r

    float acc[4][4][4];      // [s][r][jr]
    #pragma unroll
    for (int s = 0; s < 4; ++s)
        #pragma unroll
        for (int r = 0; r < 4; ++r)
            #pragma unroll
            for (int jr = 0; jr < 4; ++jr) acc[s][r][jr] = 0.0f;

    // prefetch registers: one X float4, four basis float4 per thread
    float4 pX, pC[4];
    const int xr_row = t >> 4, xr_col = (t & 15) * 4;   // Xs[16][64] cover
    #define T1_PREFETCH(i0)                                                  \
        do {                                                                 \
            pX = *(const float4*)(Xi + ((i0) + xr_row) * HN + js + xr_col);  \
            _Pragma("unroll")                                                \
            for (int rep = 0; rep < 4; ++rep) {                              \
                int idx = rep * 1024 + t * 4;                                \
                pC[rep] = *(const float4*)(Tdf + ((i0) + (idx >> 8)) * HN    \
                                           + (idx & 255));                   \
            }                                                                \
        } while (0)

    T1_PREFETCH(0);
    for (int i0 = 0; i0 < HN; i0 += 16) {
        __syncthreads();   // previous chunk's compute done, LDS reusable
        *(float4*)&Xs[xr_row][xr_col] = pX;
        #pragma unroll
        for (int rep = 0; rep < 4; ++rep) {
            int idx = rep * 1024 + t * 4;
            *(float4*)&CHs[idx >> 8][idx & 255] = pC[rep];
        }
        __syncthreads();
        if (i0 + 16 < HN) T1_PREFETCH(i0 + 16);  // overlap with compute

        #pragma unroll
        for (int ii = 0; ii < 16; ++ii) {
            float xv[4];
            *(float4*)xv = *(const float4*)&Xs[ii][4 * ci];
            float ch[4][4];
            #pragma unroll
            for (int s = 0; s < 4; ++s)
                *(float4*)ch[s] = *(const float4*)&CHs[ii][64 * s + 4 * ib];
            #pragma unroll
            for (int s = 0; s < 4; ++s)
                #pragma unroll
                for (int r = 0; r < 4; ++r)
                    #pragma unroll
                    for (int jr = 0; jr < 4; ++jr)
                        acc[s][r][jr] = fmaf(ch[s][r], xv[jr], acc[s][r][jr]);
        }
    }
    #undef T1_PREFETCH

    float* __restrict__ T1i = T1 + (size_t)img * (HN * HN);
    #pragma unroll
    for (int s = 0; s < 4; ++s)
        #pragma unroll
        for (int r = 0; r < 4; ++r)
            *(float4*)(T1i + (64 * s + 4 * ib + r) * HN + js + 4 * ci) =
                *(const float4*)acc[s][r];   // f32 intermediate (np-equal)
}

// Kernel B: Y[k1][k2] = sum_j T1[k1][j] * Tdf[j][k2]   (j ascending) + epilogue
// Block: one image x 64-wide k1-slab; thread owns 4 k1 x 16 k2 = 64 accs.
__global__ __launch_bounds__(256, 4) void y_kernel(
    const float* __restrict__ T1, const float* __restrict__ Tdf,
    const float* __restrict__ meanp, const float* __restrict__ stdp,
    float* __restrict__ out)
{
    __shared__ float Ts[16][68];    // T1 chunk TRANSPOSED [j_l][k1_l] (4.25KB)
    __shared__ float Bc[16][HN];    // basis rows j0..j0+15            (16 KB)

    const int t   = threadIdx.x;
    const int img = blockIdx.x >> 2;
    const int ks  = (blockIdx.x & 3) * 64;
    const float* __restrict__ T1i = T1 + (size_t)img * (HN * HN);

    const int ci = t & 15;   // k2 = 64*s + 4*ci + c
    const int ib = t >> 4;   // k1 = ks + 4*ib + r

    float acc[4][4][4];      // [s][r][c]
    #pragma unroll
    for (int s = 0; s < 4; ++s)
        #pragma unroll
        for (int r = 0; r < 4; ++r)
            #pragma unroll
            for (int c = 0; c < 4; ++c) acc[s][r][c] = 0.0f;

    float4 pT, pB[4];
    const int tr_row = t >> 2, tr_col = (t & 3) * 4;   // T1 rows ks..ks+63
    #define Y_PREFETCH(j0)                                                   \
        do {                                                                 \
            pT = *(const float4*)(T1i + (ks + tr_row) * HN + (j0) + tr_col); \
            _Pragma("unroll")                                                \
            for (int rep = 0; rep < 4; ++rep) {                              \
                int idx = rep * 1024 + t * 4;                                \
                pB[rep] = *(const float4*)(Tdf + ((j0) + (idx >> 8)) * HN    \
                                           + (idx & 255));                   \
            }                                                                \
        } while (0)

    Y_PREFETCH(0);
    for (int j0 = 0; j0 < HN; j0 += 16) {
        __syncthreads();
        // transposed scatter: Ts[j_local][k1_local]; 2-way bank alias = free
        Ts[tr_col + 0][tr_row] = pT.x;
        Ts[tr_col + 1][tr_row] = pT.y;
        Ts[tr_col + 2][tr_row] = pT.z;
        Ts[tr_col + 3][tr_row] = pT.w;
        #pragma unroll
        for (int rep = 0; rep < 4; ++rep) {
            int idx = rep * 1024 + t * 4;
            *(float4*)&Bc[idx >> 8][idx & 255] = pB[rep];
        }
        __syncthreads();
        if (j0 + 16 < HN) Y_PREFETCH(j0 + 16);

        #pragma unroll
        for (int p = 0; p < 16; ++p) {
            float a[4];
            *(float4*)a = *(const float4*)&Ts[p][4 * ib];  // bcast b128
            float b[4][4];
            #pragma unroll
            for (int s = 0; s < 4; ++s)
                *(float4*)b[s] = *(const float4*)&Bc[p][64 * s + 4 * ci];
            #pragma unroll
            for (int s = 0; s < 4; ++s)
                #pragma unroll
                for (int r = 0; r < 4; ++r)
                    #pragma unroll
                    for (int c = 0; c < 4; ++c)
                        acc[s][r][c] = fmaf(a[r], b[s][c], acc[s][r][c]);
        }
    }
    #undef Y_PREFETCH

    const float mean = meanp[0];
    const float stdv = stdp[0];
    float* __restrict__ O = out + (size_t)img * (HN * HN);
    #pragma unroll
    for (int s = 0; s < 4; ++s)
        #pragma unroll
        for (int r = 0; r < 4; ++r) {
            float4 v;
            v.x = (logf(fabsf(acc[s][r][0]) + 1e-13f) - mean) / stdv;
            v.y = (logf(fabsf(acc[s][r][1]) + 1e-13f) - mean) / stdv;
            v.z = (logf(fabsf(acc[s][r][2]) + 1e-13f) - mean) / stdv;
            v.w = (logf(fabsf(acc[s][r][3]) + 1e-13f) - mean) / stdv;
            *(float4*)(O + (ks + 4 * ib + r) * HN + 64 * s + 4 * ci) = v;
        }
}

// ======================= fused fallback (R3, proven) =======================
#define SLAB 32
__global__ __launch_bounds__(256, 3) void dct2_f32(
    const float* __restrict__ X, const float* __restrict__ Tdf,
    const float* __restrict__ meanp, const float* __restrict__ stdp,
    float* __restrict__ out)
{
    __shared__ union SU {
        struct { float Xs[8][HN]; float CHc[8][SLAB]; } p1;
        float Bc[16][HN];
    } u;
    __shared__ float T1s[SLAB][HN + 1];

    const int t   = threadIdx.x;
    const int img = blockIdx.x >> 3;
    const int k0  = (blockIdx.x & 7) * SLAB;
    const float* __restrict__ Xi = X + (size_t)img * (HN * HN);
    const int ci = t & 7;
    const int ib = t >> 3;

    float acc[8][4];
    #pragma unroll
    for (int q = 0; q < 8; ++q)
        #pragma unroll
        for (int r = 0; r < 4; ++r) acc[q][r] = 0.0f;

    for (int i0 = 0; i0 < HN; i0 += 8) {
        {
            int rr = t >> 5, cc = (t & 31) * 4;
            float4 a = *(const float4*)(Xi + (i0 + rr) * HN + cc);
            float4 b = *(const float4*)(Xi + (i0 + rr) * HN + cc + 128);
            *(float4*)&u.p1.Xs[rr][cc]       = a;
            *(float4*)&u.p1.Xs[rr][cc + 128] = b;
            u.p1.CHc[rr][t & 31] = Tdf[(i0 + rr) * HN + k0 + (t & 31)];
        }
        __syncthreads();
        #pragma unroll
        for (int ii = 0; ii < 8; ++ii) {
            float xr[8];
            *(float4*)&xr[0] = *(const float4*)&u.p1.Xs[ii][8 * ib];
            *(float4*)&xr[4] = *(const float4*)&u.p1.Xs[ii][8 * ib + 4];
            float ch[4];
            *(float4*)&ch[0] = *(const float4*)&u.p1.CHc[ii][4 * ci];
            #pragma unroll
            for (int q = 0; q < 8; ++q)
                #pragma unroll
                for (int r = 0; r < 4; ++r)
                    acc[q][r] = fmaf(ch[r], xr[q], acc[q][r]);
        }
        __syncthreads();
    }
    #pragma unroll
    for (int q = 0; q < 8; ++q)
        #pragma unroll
        for (int r = 0; r < 4; ++r)
            T1s[4 * ci + r][8 * ib + q] = acc[q][r];
    __syncthreads();

    float acc2[8][4];
    #pragma unroll
    for (int q = 0; q < 8; ++q)
        #pragma unroll
        for (int r = 0; r < 4; ++r) acc2[q][r] = 0.0f;

    for (int j0 = 0; j0 < HN; j0 += 16) {
        #pragma unroll
        for (int rep = 0; rep < 4; ++rep) {
            int idx = rep * 1024 + t * 4;
            int p = idx >> 8, c = idx & 255;
            *(float4*)&u.Bc[p][c] = *(const float4*)(Tdf + (j0 + p) * HN + c);
        }
        __syncthreads();
        #pragma unroll
        for (int p = 0; p < 16; ++p) {
            float a[4];
            #pragma unroll
            for (int r = 0; r < 4; ++r) a[r] = T1s[4 * ci + r][j0 + p];
            float b[8];
            *(float4*)&b[0] = *(const float4*)&u.Bc[p][8 * ib];
            *(float4*)&b[4] = *(const float4*)&u.Bc[p][8 * ib + 4];
            #pragma unroll
            for (int q = 0; q < 8; ++q)
                #pragma unroll
                for (int r = 0; r < 4; ++r)
                    acc2[q][r] = fmaf(a[r], b[q], acc2[q][r]);
        }
        __syncthreads();
    }

    const float mean = meanp[0];
    const float stdv = stdp[0];
    #pragma unroll
    for (int q = 0; q < 8; ++q)
        #pragma unroll
        for (int r = 0; r < 4; ++r) {
            float v = (logf(fabsf(acc2[q][r]) + 1e-13f) - mean) / stdv;
            T1s[4 * ci + r][8 * ib + q] = v;
        }
    __syncthreads();

    float* __restrict__ O = out + (size_t)img * (HN * HN) + (size_t)k0 * HN;
    #pragma unroll
    for (int rep = 0; rep < 8; ++rep) {
        int idx = rep * 1024 + t * 4;
        int row = idx >> 8, col = idx & 255;
        float4 v = make_float4(T1s[row][col], T1s[row][col + 1],
                               T1s[row][col + 2], T1s[row][col + 3]);
        *(float4*)(O + row * HN + col) = v;
    }
}

extern "C" void kernel_launch(void* const* d_in, const int* in_sizes, int n_in,
                              void* d_out, int out_size, void* d_ws, size_t ws_size,
                              hipStream_t stream) {
    const float* X     = (const float*)d_in[0];
    const float* meanp = (const float*)d_in[1];
    const float* stdp  = (const float*)d_in[2];

    float* Tdf = (float*)d_ws;                       // 256 KB basis
    const size_t T1_OFF    = 256 * 1024;
    const size_t T1_BYTES  = (size_t)NIMG * HN * HN * sizeof(float);  // 100.7MB

    basis_init<<<256, 256, 0, stream>>>(Tdf);

    if (ws_size >= T1_OFF + T1_BYTES) {
        float* T1 = (float*)((char*)d_ws + T1_OFF);
        t1_kernel<<<NIMG * 4, 256, 0, stream>>>(X, Tdf, T1);
        y_kernel <<<NIMG * 4, 256, 0, stream>>>(T1, Tdf, meanp, stdp,
                                                (float*)d_out);
    } else {
        dct2_f32<<<NIMG * 8, 256, 0, stream>>>(X, Tdf, meanp, stdp,
                                               (float*)d_out);
    }
}